// Round 13
// baseline (815.791 us; speedup 1.0000x reference)
//
#include <hip/hip_runtime.h>
#include <cstdint>
#include <cstddef>

typedef unsigned short u16;
typedef unsigned int   u32;

#define D_MODEL 1024
#define D_INNER 2048
#define BATCH   8
#define TSEQ    2048
#define MROWS   (BATCH*TSEQ)      // 16384 rows for all GEMMs
#define CHUNK   32
#define NCHUNK  (TSEQ/CHUNK)      // 64
#define EDIM    (BATCH*D_INNER)   // 16384 scan lanes

typedef float  f32x4  __attribute__((ext_vector_type(4)));
typedef __bf16 bf16x8 __attribute__((ext_vector_type(8)));
typedef short  s16x8  __attribute__((ext_vector_type(8)));

__device__ __forceinline__ float bf2f(u16 u){ return __builtin_bit_cast(float, (u32)u << 16); }
__device__ __forceinline__ u16 f2bf(float f){
  u32 u = __builtin_bit_cast(u32, f);
  u += 0x7fffu + ((u >> 16) & 1u);
  return (u16)(u >> 16);
}
__device__ __forceinline__ float sigm(float x){ return 1.0f/(1.0f + __expf(-x)); }

__device__ __forceinline__ void gld16(const u16* g, u16* l){
  __builtin_amdgcn_global_load_lds((const __attribute__((address_space(1))) void*)g,
                                   (__attribute__((address_space(3))) void*)l, 16, 0, 0);
}

__device__ __forceinline__ s16x8 cvt8(const float* s){
  float4 u0 = *(const float4*)s;
  float4 u1 = *(const float4*)(s + 4);
  s16x8 p;
  p[0]=(short)f2bf(u0.x); p[1]=(short)f2bf(u0.y);
  p[2]=(short)f2bf(u0.z); p[3]=(short)f2bf(u0.w);
  p[4]=(short)f2bf(u1.x); p[5]=(short)f2bf(u1.y);
  p[6]=(short)f2bf(u1.z); p[7]=(short)f2bf(u1.w);
  return p;
}

// ===========================================================================
// 256x256 GEMM, BK=64, A in double-buffered LDS (64 KB), B DIRECT FROM L2
// into registers (weights: consecutive blocks share the same 1 MB B-slab ->
// L2-resident).  Removes B from the saturated LDS pipe (192->128 KB/K-tile)
// and halves LDS footprint.  r9's proven single-barrier skeleton:
//   loop t: vmcnt(0) [A-stage(t)+B-loads(t), issued ~1 tile ago, landed]
//           barrier [publish A buf]
//           stageA(t+1) sets 0,1 (4 gld16)
//           per half: 8 ds_read A frags + 32 MFMA vs B regs
//           sched_barrier; loadB(t+1) into same regs (after last MFMA use)
// A swizzle (0-conflict, r6/r7/r12-verified): global source col ^= (row&7)
// at 16B granularity; read col byte ^= (l15&7)<<4.  B needs no swizzle.
// MODE 0: silu -> bf16 | 3: f32 out, row remap (t,b)->(b,t) | 4: fused
// alpha|v (N=4096): col<2048 -> sigmoid(+bias)->Cout, else +bias2->Cout2.
// ===========================================================================
template<int MODE, int K, int N>
__global__ __launch_bounds__(512, 2) void gemm256(
    const u16* __restrict__ A, const u16* __restrict__ Bt,
    const float* __restrict__ bias, const float* __restrict__ bias2,
    void* __restrict__ Cout, void* __restrict__ Cout2)
{
  __shared__ __align__(16) u16 sA[2][16384];   // A only, double-buffered, 64 KB
  constexpr int NT = K/64;
  const int tid = threadIdx.x;
  const int w = tid >> 6, lane = tid & 63;
  const int wr = w >> 2, wc = w & 3;               // 2 x 4 wave grid
  const int l15 = lane & 15, kg = lane >> 4;
  const int bm = blockIdx.x, bn = blockIdx.y;

  // ---- A staging: linear LDS dest; inverse-swizzled global source ----
  const int st_rw   = lane >> 3;                  // == row&7 for this lane
  const int st_cole = ((lane&7) ^ st_rw) << 3;    // swizzled bf16 col element
  const size_t a_base = (size_t)(bm*256)*K + st_cole;

  // A-set s = rows {s*64+[0,64)} u {128+s*64+[0,64)} (read-aligned, r7/r12)
  auto stageA = [&](int buf, int kt, int set){
    u16* dst = &sA[buf][set*4096 + w*512];        // wave-uniform base
    #pragma unroll
    for (int i = 0; i < 2; ++i){
      const int row = set*64 + i*128 + w*8 + st_rw;   // row&7 == st_rw
      gld16(A + a_base + (size_t)row*K + kt*64, dst + i*8192);
    }
  };

  // ---- B direct from global (L2-resident weights), per-lane fragments ----
  // lane (l15,kg) of wave wc holds Bt[wc*64 + ni*16 + l15][kt*64 + ks*32 + kg*8 ..+8]
  const u16* bptr = Bt + (size_t)(bn*256 + wc*64 + l15)*K + kg*8;
  s16x8 bf[4][2];
  auto loadB = [&](int kt){
    #pragma unroll
    for (int ni = 0; ni < 4; ++ni)
      #pragma unroll
      for (int ks = 0; ks < 2; ++ks)
        bf[ni][ks] = *(const s16x8*)(bptr + (size_t)ni*16*K + kt*64 + ks*32);
  };

  // ---- A read-side swizzled col bytes (ks=0); ks=1 = csw^64 ----
  const int csw = (kg*16) ^ ((l15&7)<<4);

  f32x4 acc[8][4] = {};

  // ---- prologue: stage A(0) both sets; load B(0) ----
  stageA(0,0,0); stageA(0,0,1);
  loadB(0);

  for (int t = 0; t < NT; ++t){
    const char* As = (const char*)&sA[t&1][0];
    const int nb = (t+1)&1;

    asm volatile("s_waitcnt vmcnt(0)" ::: "memory");   // A(t)+B(t) landed
    __builtin_amdgcn_s_barrier();                       // publish A buf[t&1]

    if (t < NT-1){ stageA(nb,t+1,0); stageA(nb,t+1,1); }

    // A fragments per 64-row half (8 ds_read_b128) + 32 MFMA per half
    #pragma unroll
    for (int mh = 0; mh < 2; ++mh){
      s16x8 af[4][2];
      #pragma unroll
      for (int mf = 0; mf < 4; ++mf){
        af[mf][0] = *(const s16x8*)(As + (wr*128 + mh*64 + mf*16 + l15)*128 + csw);
        af[mf][1] = *(const s16x8*)(As + (wr*128 + mh*64 + mf*16 + l15)*128 + (csw^64));
      }
      #pragma unroll
      for (int mf = 0; mf < 4; ++mf)
        #pragma unroll
        for (int ni = 0; ni < 4; ++ni)
          #pragma unroll
          for (int ks = 0; ks < 2; ++ks)
            acc[mh*4+mf][ni] = __builtin_amdgcn_mfma_f32_16x16x32_bf16(
                __builtin_bit_cast(bf16x8, af[mf][ks]),
                __builtin_bit_cast(bf16x8, bf[ni][ks]),
                acc[mh*4+mf][ni], 0, 0, 0);
    }

    // refill B regs for t+1 AFTER their last MFMA use (WAR-safe in-order);
    // sched_barrier keeps the loads from hoisting above the MFMAs.
    __builtin_amdgcn_sched_barrier(0);
    if (t < NT-1) loadB(t+1);
  }

  // ---- epilogue ----
  #pragma unroll
  for (int mi = 0; mi < 8; ++mi){
    #pragma unroll
    for (int ni = 0; ni < 4; ++ni){
      #pragma unroll
      for (int r = 0; r < 4; ++r){
        const int row = bm*256 + wr*128 + mi*16 + kg*4 + r;
        const int col = bn*256 + wc*64 + ni*16 + l15;
        float val = acc[mi][ni][r];
        if constexpr (MODE == 0){
          val = val * sigm(val);
          ((u16*)Cout)[(size_t)row*N + col] = f2bf(val);
        } else if constexpr (MODE == 3){
          const int orow = (row & 7)*TSEQ + (row >> 3);   // (t,b) -> (b,t)
          ((float*)Cout)[(size_t)orow*N + col] = val;
        } else if constexpr (MODE == 4){
          if (col < D_INNER){
            val = sigm(val + bias[col]);
            ((u16*)Cout)[(size_t)row*D_INNER + col] = f2bf(val);
          } else {
            val = val + bias2[col - D_INNER];
            ((u16*)Cout2)[(size_t)row*D_INNER + (col - D_INNER)] = f2bf(val);
          }
        }
      }
    }
  }
}

// ---------------------------------------------------------------------------
// Fallback GEMM (round-2 proven, 128x128 m97 structure)
// ---------------------------------------------------------------------------
template<int MODE, int K, int N, bool BA, bool BB>
__global__ __launch_bounds__(256) void gemm_bt(
    const void* __restrict__ Ap, const void* __restrict__ Bp,
    const float* __restrict__ bias, void* __restrict__ Cout)
{
  __shared__ __align__(16) u16 sA[128*32];
  __shared__ __align__(16) u16 sB[128*32];
  const int tid = threadIdx.x;
  const int bm = blockIdx.x, bn = blockIdx.y;
  const int w = tid >> 6, lane = tid & 63;
  const int wr = w >> 1, wc = w & 1;
  const int l15 = lane & 15, kg = lane >> 4;
  const int r0   = tid >> 2;
  const int koff = (tid & 3) * 8;

  int ga[2];
  #pragma unroll
  for (int i = 0; i < 2; ++i){
    int mc = bm*128 + r0 + i*64;
    if (MODE == 0)      ga[i] = (mc & 7) * TSEQ + (mc >> 3);
    else if (MODE == 3) ga[i] = (mc & (TSEQ-1)) * BATCH + (mc >> 11);
    else                ga[i] = mc;
  }
  const u16*   Abf = (const u16*)Ap;
  const float* Af  = (const float*)Ap;
  const u16*   Bbf = (const u16*)Bp;
  const float* Bf  = (const float*)Bp;
  u16* la[2] = { sA + w*512, sA + 2048 + w*512 };
  u16* lb[2] = { sB + w*512, sB + 2048 + w*512 };
  u16* ldsA = sA + tid*8;
  u16* ldsB = sB + tid*8;
  const int gb[2] = { bn*128 + r0, bn*128 + r0 + 64 };

  f32x4 acc[4][4] = {};
  for (int kt = 0; kt < K/32; ++kt){
    __syncthreads();
    if constexpr (BA){
      gld16(Abf + (size_t)ga[0]*K + koff + kt*32, la[0]);
      gld16(Abf + (size_t)ga[1]*K + koff + kt*32, la[1]);
    } else {
      #pragma unroll
      for (int i = 0; i < 2; ++i)
        *(s16x8*)(ldsA + i*2048) = cvt8(Af + (size_t)ga[i]*K + koff + kt*32);
    }
    if constexpr (BB){
      gld16(Bbf + (size_t)gb[0]*K + koff + kt*32, lb[0]);
      gld16(Bbf + (size_t)gb[1]*K + koff + kt*32, lb[1]);
    } else {
      #pragma unroll
      for (int i = 0; i < 2; ++i)
        *(s16x8*)(ldsB + i*2048) = cvt8(Bf + (size_t)gb[i]*K + koff + kt*32);
    }
    __syncthreads();

    s16x8 af[4], bfr[4];
    #pragma unroll
    for (int m = 0; m < 4; ++m)
      af[m] = *(const s16x8*)(sA + (wr*64 + m*16 + l15)*32 + kg*8);
    #pragma unroll
    for (int n = 0; n < 4; ++n)
      bfr[n] = *(const s16x8*)(sB + (wc*64 + n*16 + l15)*32 + kg*8);
    #pragma unroll
    for (int m = 0; m < 4; ++m)
      #pragma unroll
      for (int n = 0; n < 4; ++n)
        acc[m][n] = __builtin_amdgcn_mfma_f32_16x16x32_bf16(
            __builtin_bit_cast(bf16x8, af[m]),
            __builtin_bit_cast(bf16x8, bfr[n]),
            acc[m][n], 0, 0, 0);
  }
  #pragma unroll
  for (int m = 0; m < 4; ++m)
    #pragma unroll
    for (int n = 0; n < 4; ++n)
      #pragma unroll
      for (int r = 0; r < 4; ++r){
        const int row = bm*128 + wr*64 + m*16 + kg*4 + r;
        const int col = bn*128 + wc*64 + n*16 + l15;
        float val = acc[m][n][r];
        if constexpr (MODE == 0){
          val = val * sigm(val);
          ((u16*)Cout)[(size_t)row*N + col] = f2bf(val);
        } else if constexpr (MODE == 1){
          val = sigm(val + bias[col]);
          ((u16*)Cout)[(size_t)row*N + col] = f2bf(val);
        } else if constexpr (MODE == 2){
          val = val + bias[col];
          ((u16*)Cout)[(size_t)row*N + col] = f2bf(val);
        } else {
          ((float*)Cout)[(size_t)row*N + col] = val;
        }
      }
}

// ---------------------------------------------------------------------------
// chunk-parallel linear scan: h_t = a_t * h_{t-1} + (1-a_t) * v_t
// ---------------------------------------------------------------------------
__global__ __launch_bounds__(256) void scan_pass1(
    const u16* __restrict__ alpha, const u16* __restrict__ v,
    float* __restrict__ P, float* __restrict__ H)
{
  const int e = blockIdx.x*256 + threadIdx.x;
  const int c = blockIdx.y;
  const size_t base = (size_t)c*CHUNK*EDIM + e;
  float p = 1.f, h = 0.f;
  #pragma unroll 8
  for (int t = 0; t < CHUNK; ++t){
    float a  = bf2f(alpha[base + (size_t)t*EDIM]);
    float vv = bf2f(v[base + (size_t)t*EDIM]);
    p *= a;
    h = a*h + (1.f - a)*vv;
  }
  P[(size_t)c*EDIM + e] = p;
  H[(size_t)c*EDIM + e] = h;
}

__global__ __launch_bounds__(256) void scan_pass2(
    const float* __restrict__ P, const float* __restrict__ H,
    const float* __restrict__ h0, float* __restrict__ hstart,
    float* __restrict__ hfinal)
{
  const int e = blockIdx.x*256 + threadIdx.x;
  float hs = h0[e];
  for (int c = 0; c < NCHUNK; ++c){
    hstart[(size_t)c*EDIM + e] = hs;
    hs = P[(size_t)c*EDIM + e]*hs + H[(size_t)c*EDIM + e];
  }
  hfinal[e] = hs;
}

__global__ __launch_bounds__(256) void scan_pass3(
    const u16* __restrict__ alpha, const u16* __restrict__ v,
    const float* __restrict__ hstart, u16* __restrict__ outs)
{
  const int e = blockIdx.x*256 + threadIdx.x;
  const int c = blockIdx.y;
  const size_t base = (size_t)c*CHUNK*EDIM + e;
  float h = hstart[(size_t)c*EDIM + e];
  #pragma unroll 8
  for (int t = 0; t < CHUNK; ++t){
    float a  = bf2f(alpha[base + (size_t)t*EDIM]);
    float vv = bf2f(v[base + (size_t)t*EDIM]);
    h = a*h + (1.f - a)*vv;
    float o = h*h*sigm(h);            // h * silu(h)
    outs[base + (size_t)t*EDIM] = f2bf(o);   // aliases v: write-after-read, same slot
  }
}

// ---------------------------------------------------------------------------
__global__ __launch_bounds__(256) void cvt_bf16(
    const float* __restrict__ src, u16* __restrict__ dst, int n4)
{
  const int i = blockIdx.x*256 + threadIdx.x;
  if (i >= n4) return;
  const float4 f = ((const float4*)src)[i];
  u32 w0 = (u32)f2bf(f.x) | ((u32)f2bf(f.y) << 16);
  u32 w1 = (u32)f2bf(f.z) | ((u32)f2bf(f.w) << 16);
  ((uint2*)dst)[i] = make_uint2(w0, w1);
}

// x [B][T][D] f32 -> bf16 time-major rows (t*8+b)
__global__ __launch_bounds__(256) void cvt_x_tm(
    const float* __restrict__ src, u16* __restrict__ dst)
{
  const int i = blockIdx.x*256 + threadIdx.x;    // float4 index
  const int d4  = i & 255;                        // 256 float4 per row
  const int rin = i >> 8;                         // b*TSEQ + t
  const int b = rin >> 11, tt = rin & (TSEQ-1);
  const int rout = tt*BATCH + b;
  const float4 f = ((const float4*)src)[i];
  u32 w0 = (u32)f2bf(f.x) | ((u32)f2bf(f.y) << 16);
  u32 w1 = (u32)f2bf(f.z) | ((u32)f2bf(f.w) << 16);
  ((uint2*)dst)[(size_t)rout*256 + d4] = make_uint2(w0, w1);
}

// ---------------------------------------------------------------------------
extern "C" void kernel_launch(void* const* d_in, const int* in_sizes, int n_in,
                              void* d_out, int out_size, void* d_ws, size_t ws_size,
                              hipStream_t stream)
{
  const float* x     = (const float*)d_in[0];
  const float* h0    = (const float*)d_in[1];
  const float* W_in  = (const float*)d_in[2];
  const float* W_al  = (const float*)d_in[3];
  const float* b_al  = (const float*)d_in[4];
  const float* W_v   = (const float*)d_in[5];
  const float* b_v   = (const float*)d_in[6];
  const float* W_out = (const float*)d_in[7];

  float* out  = (float*)d_out;
  float* hfin = out + (size_t)MROWS*D_MODEL;   // h_final tail of d_out

  const size_t SZ_ACT = (size_t)MROWS*D_INNER*2;   // 67,108,864 B
  const size_t SZ_ST  = (size_t)NCHUNK*EDIM*4;     //  4,194,304 B
  const size_t SZ_WI  = (size_t)D_INNER*D_MODEL*2; //  4 MB
  const size_t SZ_WA  = (size_t)D_INNER*D_INNER*2; //  8 MB
  const size_t need_min  = 3*SZ_ACT + 3*SZ_ST;                   // ~214 MB (proven)
  const size_t need_fast = need_min + 2*SZ_WI + 2*SZ_WA + 8192;  // ~239 MB (proven)

  if (ws_size < need_min) return;

  char* ws = (char*)d_ws;
  auto carve = [&](size_t bytes){
    char* p = ws; ws += (bytes + 255) & ~(size_t)255; return p;
  };
  u16* xp   = (u16*)carve(SZ_ACT);   // silu(in_proj), layout [T, B*D_inner]
  u16* alp  = (u16*)carve(SZ_ACT);
  u16* vv   = (u16*)carve(SZ_ACT);   // v; pass3 overwrites in place with outs
  float* P  = (float*)carve(SZ_ST);
  float* H  = (float*)carve(SZ_ST);
  float* hs = (float*)carve(SZ_ST);

  const dim3 gScan(EDIM/256, NCHUNK);

  auto cvt = [&](const float* s, u16* d, size_t n){
    int n4 = (int)(n/4);
    cvt_bf16<<<(n4+255)/256, 256, 0, stream>>>(s, d, n4);
  };

  if (ws_size >= need_fast){
    // ---- fast path: bf16 weights (wab||wvb adjacent => fused N=4096 GEMM),
    // time-major bf16 x aliasing alp (lifetime ends before alpha write).
    u16* wib = (u16*)carve(SZ_WI);
    u16* wab = (u16*)carve(SZ_WA);
    u16* wvb = (u16*)carve(SZ_WA);   // = wab + D_INNER rows (contiguous)
    u16* wob = (u16*)carve(SZ_WI);
    u16* xb  = alp;

    cvt_x_tm<<<(MROWS*D_MODEL/4)/256, 256, 0, stream>>>(x, xb);
    cvt(W_in,  wib, (size_t)D_INNER*D_MODEL);
    cvt(W_al,  wab, (size_t)D_INNER*D_INNER);
    cvt(W_v,   wvb, (size_t)D_INNER*D_INNER);
    cvt(W_out, wob, (size_t)D_MODEL*D_INNER);

    gemm256<0, D_MODEL, D_INNER><<<dim3(MROWS/256, D_INNER/256), 512, 0, stream>>>(
        xb, wib, nullptr, nullptr, xp, nullptr);
    gemm256<4, D_INNER, 2*D_INNER><<<dim3(MROWS/256, 2*D_INNER/256), 512, 0, stream>>>(
        xp, wab, b_al, b_v, alp, vv);

    scan_pass1<<<gScan, 256, 0, stream>>>(alp, vv, P, H);
    scan_pass2<<<EDIM/256, 256, 0, stream>>>(P, H, h0, hs, hfin);
    scan_pass3<<<gScan, 256, 0, stream>>>(alp, vv, hs, vv);

    gemm256<3, D_INNER, D_MODEL><<<dim3(MROWS/256, D_MODEL/256), 512, 0, stream>>>(
        vv, wob, nullptr, nullptr, out, nullptr);
  } else {
    // ---- fallback: round-2 proven path ----
    const dim3 gBig(MROWS/128, D_INNER/128);
    const dim3 gOut(MROWS/128, D_MODEL/128);
    gemm_bt<0, D_MODEL, D_INNER, false, false><<<gBig, 256, 0, stream>>>(x,  W_in, nullptr, xp);
    gemm_bt<1, D_INNER, D_INNER, true,  false><<<gBig, 256, 0, stream>>>(xp, W_al, b_al,    alp);
    gemm_bt<2, D_INNER, D_INNER, true,  false><<<gBig, 256, 0, stream>>>(xp, W_v,  b_v,     vv);

    scan_pass1<<<gScan, 256, 0, stream>>>(alp, vv, P, H);
    scan_pass2<<<EDIM/256, 256, 0, stream>>>(P, H, h0, hs, hfin);
    scan_pass3<<<gScan, 256, 0, stream>>>(alp, vv, hs, vv);

    gemm_bt<3, D_INNER, D_MODEL, true, false><<<gOut, 256, 0, stream>>>(vv, W_out, nullptr, out);
  }
}

// Round 14
// 537.281 us; speedup vs baseline: 1.5184x; 1.5184x over previous
//
#include <hip/hip_runtime.h>
#include <cstdint>
#include <cstddef>

typedef unsigned short u16;
typedef unsigned int   u32;

#define D_MODEL 1024
#define D_INNER 2048
#define BATCH   8
#define TSEQ    2048
#define MROWS   (BATCH*TSEQ)      // 16384 rows for all GEMMs
#define CHUNK   32
#define NCHUNK  (TSEQ/CHUNK)      // 64
#define EDIM    (BATCH*D_INNER)   // 16384 scan lanes

typedef float  f32x4  __attribute__((ext_vector_type(4)));
typedef __bf16 bf16x8 __attribute__((ext_vector_type(8)));
typedef short  s16x8  __attribute__((ext_vector_type(8)));

__device__ __forceinline__ float bf2f(u16 u){ return __builtin_bit_cast(float, (u32)u << 16); }
__device__ __forceinline__ u16 f2bf(float f){
  u32 u = __builtin_bit_cast(u32, f);
  u += 0x7fffu + ((u >> 16) & 1u);
  return (u16)(u >> 16);
}
__device__ __forceinline__ float sigm(float x){ return 1.0f/(1.0f + __expf(-x)); }

__device__ __forceinline__ void gld16(const u16* g, u16* l){
  __builtin_amdgcn_global_load_lds((const __attribute__((address_space(1))) void*)g,
                                   (__attribute__((address_space(3))) void*)l, 16, 0, 0);
}

__device__ __forceinline__ s16x8 cvt8(const float* s){
  float4 u0 = *(const float4*)s;
  float4 u1 = *(const float4*)(s + 4);
  s16x8 p;
  p[0]=(short)f2bf(u0.x); p[1]=(short)f2bf(u0.y);
  p[2]=(short)f2bf(u0.z); p[3]=(short)f2bf(u0.w);
  p[4]=(short)f2bf(u1.x); p[5]=(short)f2bf(u1.y);
  p[6]=(short)f2bf(u1.z); p[7]=(short)f2bf(u1.w);
  return p;
}

// ===========================================================================
// 256x256 4-phase/K-tile GEMM (r7 session-best, restored verbatim).
// BK=64, 512 thr, 8 waves (2x4).  T2 swizzle (0-conflict verified):
// LDS linear dest, global source col pre-XORed by row&7 (16B granularity);
// read col byte XORed the same way.  Read-aligned stage sets:
//   A-set s = rows {s*64+[0,64)} u {128+s*64+[0,64)}  == LOADA(.,s) reads
//   B-set s = rows with bit5==s                        == LOADB(.,s) reads
// Schedule (stages for tile t+1 during tile t):
//   q0: Bset0,Aset0 issue; vmcnt(6)   [Bset1(t) landed]
//   q1: Bset1 issue;       vmcnt(6)   [Aset1(t) landed]
//   q2: Aset1 issue;       no wait
//   q3:                    vmcnt(4)   [Bset0,Aset0(t+1) landed]
// Every stage gets >=3 phases of flight; queue never drains to 0.
// MODE 0: silu -> bf16 | 3: f32 out, row remap (t,b)->(b,t) | 4: fused
// alpha|v (N=4096): col<2048 -> sigmoid(+bias)->Cout, else +bias2->Cout2.
// ===========================================================================
#define LOADA(AF, MH) \
  _Pragma("unroll") \
  for (int mf = 0; mf < 4; ++mf){ \
    AF[mf][0] = *(const s16x8*)(As + (wr*128 + (MH)*64 + mf*16 + l15)*128 + csw); \
    AF[mf][1] = *(const s16x8*)(As + (wr*128 + (MH)*64 + mf*16 + l15)*128 + (csw^64)); \
  }
#define LOADB(BF, NH) \
  _Pragma("unroll") \
  for (int nf = 0; nf < 2; ++nf){ \
    BF[nf][0] = *(const s16x8*)(Bs + (wc*64 + (NH)*32 + nf*16 + l15)*128 + csw); \
    BF[nf][1] = *(const s16x8*)(Bs + (wc*64 + (NH)*32 + nf*16 + l15)*128 + (csw^64)); \
  }
#define MFMAQ(AF, BF, MH, NH) \
  __builtin_amdgcn_s_setprio(1); \
  _Pragma("unroll") \
  for (int mf = 0; mf < 4; ++mf) \
    _Pragma("unroll") \
    for (int nf = 0; nf < 2; ++nf) \
      _Pragma("unroll") \
      for (int ks = 0; ks < 2; ++ks) \
        acc[(MH)*4+mf][(NH)*2+nf] = __builtin_amdgcn_mfma_f32_16x16x32_bf16( \
            __builtin_bit_cast(bf16x8, AF[mf][ks]), \
            __builtin_bit_cast(bf16x8, BF[nf][ks]), \
            acc[(MH)*4+mf][(NH)*2+nf], 0, 0, 0); \
  __builtin_amdgcn_s_setprio(0);

template<int MODE, int K, int N>
__global__ __launch_bounds__(512, 2) void gemm256(
    const u16* __restrict__ A, const u16* __restrict__ Bt,
    const float* __restrict__ bias, const float* __restrict__ bias2,
    void* __restrict__ Cout, void* __restrict__ Cout2)
{
  __shared__ __align__(16) u16 sAB[2][2][16384];   // [op A/B][buf][32KB tile]
  constexpr int NT = K/64;
  const int tid = threadIdx.x;
  const int w = tid >> 6, lane = tid & 63;
  const int wr = w >> 2, wc = w & 3;               // 2 x 4 wave grid
  const int l15 = lane & 15, kg = lane >> 4;
  const int bm = blockIdx.x, bn = blockIdx.y;

  // ---- staging: linear LDS dest; inverse-swizzled global source ----
  const int st_rw   = lane >> 3;                  // per-lane row offset; == row&7
  const int st_cole = ((lane&7) ^ st_rw) << 3;    // swizzled bf16 col element
  const size_t a_base = (size_t)(bm*256)*K + st_cole;
  const size_t b_base = (size_t)(bn*256)*K + st_cole;

  auto stageA = [&](int buf, int kt, int set){
    u16* dst = &sAB[0][buf][set*4096 + w*512];    // wave-uniform base
    #pragma unroll
    for (int i = 0; i < 2; ++i){
      const int row = set*64 + i*128 + w*8 + st_rw;   // row&7 == st_rw
      gld16(A + a_base + (size_t)row*K + kt*64, dst + i*8192);
    }
  };
  auto stageB = [&](int buf, int kt, int set){
    #pragma unroll
    for (int i = 0; i < 2; ++i){
      const int g = i*64 + w*8;
      const int rowbase = (g>>5)*64 + set*32 + (g&31);   // rowbase&7 == 0
      gld16(Bt + b_base + (size_t)(rowbase + st_rw)*K + kt*64,
            &sAB[1][buf][rowbase*64]);
    }
  };

  // ---- read-side swizzled col bytes (ks=0); ks=1 = csw^64 ----
  const int csw = (kg*16) ^ ((l15&7)<<4);

  f32x4 acc[8][4] = {};

  // ---- prologue: tile 0 in set order Bset0,Aset0,Bset1,Aset1 ----
  stageB(0,0,0); stageA(0,0,0); stageB(0,0,1); stageA(0,0,1);
  asm volatile("s_waitcnt vmcnt(4)" ::: "memory");   // Bset0+Aset0 landed
  __builtin_amdgcn_s_barrier();

  for (int t = 0; t < NT; ++t){
    const char* As = (const char*)&sAB[0][t&1][0];
    const char* Bs = (const char*)&sAB[1][t&1][0];
    const int nb = (t+1)&1;
    const bool more = (t < NT-1);
    s16x8 af[4][2], bf0[2][2], bf1[2][2];

    // q0: read A(set0)+B(set0); stage Bset0,Aset0 of t+1
    LOADA(af, 0)
    LOADB(bf0, 0)
    if (more){
      stageB(nb, t+1, 0); stageA(nb, t+1, 0);
      asm volatile("s_waitcnt vmcnt(6)" ::: "memory");   // Bset1(t) landed
    } else {
      asm volatile("s_waitcnt vmcnt(2)" ::: "memory");
    }
    __builtin_amdgcn_s_barrier();
    MFMAQ(af, bf0, 0, 0)
    __builtin_amdgcn_s_barrier();

    // q1: read B(set1); stage Bset1 of t+1
    LOADB(bf1, 1)
    if (more){
      stageB(nb, t+1, 1);
      asm volatile("s_waitcnt vmcnt(6)" ::: "memory");   // Aset1(t) landed
    } else {
      asm volatile("s_waitcnt vmcnt(0)" ::: "memory");
    }
    __builtin_amdgcn_s_barrier();
    MFMAQ(af, bf1, 0, 1)
    __builtin_amdgcn_s_barrier();

    // q2: read A(set1); stage Aset1 of t+1 (no wait)
    LOADA(af, 1)
    if (more){ stageA(nb, t+1, 1); }
    __builtin_amdgcn_s_barrier();
    MFMAQ(af, bf1, 1, 1)
    __builtin_amdgcn_s_barrier();

    // q3: counted wait for t+1's first sets (issued 3 phases ago)
    if (more){
      asm volatile("s_waitcnt vmcnt(4)" ::: "memory");   // Bset0+Aset0(t+1)
    }
    __builtin_amdgcn_s_barrier();
    MFMAQ(af, bf0, 1, 0)
    __builtin_amdgcn_s_barrier();
  }

  // ---- epilogue ----
  #pragma unroll
  for (int mi = 0; mi < 8; ++mi){
    #pragma unroll
    for (int ni = 0; ni < 4; ++ni){
      #pragma unroll
      for (int r = 0; r < 4; ++r){
        const int row = bm*256 + wr*128 + mi*16 + kg*4 + r;
        const int col = bn*256 + wc*64 + ni*16 + l15;
        float val = acc[mi][ni][r];
        if constexpr (MODE == 0){
          val = val * sigm(val);
          ((u16*)Cout)[(size_t)row*N + col] = f2bf(val);
        } else if constexpr (MODE == 3){
          const int orow = (row & 7)*TSEQ + (row >> 3);   // (t,b) -> (b,t)
          ((float*)Cout)[(size_t)orow*N + col] = val;
        } else if constexpr (MODE == 4){
          if (col < D_INNER){
            val = sigm(val + bias[col]);
            ((u16*)Cout)[(size_t)row*D_INNER + col] = f2bf(val);
          } else {
            val = val + bias2[col - D_INNER];
            ((u16*)Cout2)[(size_t)row*D_INNER + (col - D_INNER)] = f2bf(val);
          }
        }
      }
    }
  }
}

// ---------------------------------------------------------------------------
// Fallback GEMM (round-2 proven, 128x128 m97 structure)
// ---------------------------------------------------------------------------
template<int MODE, int K, int N, bool BA, bool BB>
__global__ __launch_bounds__(256) void gemm_bt(
    const void* __restrict__ Ap, const void* __restrict__ Bp,
    const float* __restrict__ bias, void* __restrict__ Cout)
{
  __shared__ __align__(16) u16 sA[128*32];
  __shared__ __align__(16) u16 sB[128*32];
  const int tid = threadIdx.x;
  const int bm = blockIdx.x, bn = blockIdx.y;
  const int w = tid >> 6, lane = tid & 63;
  const int wr = w >> 1, wc = w & 1;
  const int l15 = lane & 15, kg = lane >> 4;
  const int r0   = tid >> 2;
  const int koff = (tid & 3) * 8;

  int ga[2];
  #pragma unroll
  for (int i = 0; i < 2; ++i){
    int mc = bm*128 + r0 + i*64;
    if (MODE == 0)      ga[i] = (mc & 7) * TSEQ + (mc >> 3);
    else if (MODE == 3) ga[i] = (mc & (TSEQ-1)) * BATCH + (mc >> 11);
    else                ga[i] = mc;
  }
  const u16*   Abf = (const u16*)Ap;
  const float* Af  = (const float*)Ap;
  const u16*   Bbf = (const u16*)Bp;
  const float* Bf  = (const float*)Bp;
  u16* la[2] = { sA + w*512, sA + 2048 + w*512 };
  u16* lb[2] = { sB + w*512, sB + 2048 + w*512 };
  u16* ldsA = sA + tid*8;
  u16* ldsB = sB + tid*8;
  const int gb[2] = { bn*128 + r0, bn*128 + r0 + 64 };

  f32x4 acc[4][4] = {};
  for (int kt = 0; kt < K/32; ++kt){
    __syncthreads();
    if constexpr (BA){
      gld16(Abf + (size_t)ga[0]*K + koff + kt*32, la[0]);
      gld16(Abf + (size_t)ga[1]*K + koff + kt*32, la[1]);
    } else {
      #pragma unroll
      for (int i = 0; i < 2; ++i)
        *(s16x8*)(ldsA + i*2048) = cvt8(Af + (size_t)ga[i]*K + koff + kt*32);
    }
    if constexpr (BB){
      gld16(Bbf + (size_t)gb[0]*K + koff + kt*32, lb[0]);
      gld16(Bbf + (size_t)gb[1]*K + koff + kt*32, lb[1]);
    } else {
      #pragma unroll
      for (int i = 0; i < 2; ++i)
        *(s16x8*)(ldsB + i*2048) = cvt8(Bf + (size_t)gb[i]*K + koff + kt*32);
    }
    __syncthreads();

    s16x8 af[4], bfr[4];
    #pragma unroll
    for (int m = 0; m < 4; ++m)
      af[m] = *(const s16x8*)(sA + (wr*64 + m*16 + l15)*32 + kg*8);
    #pragma unroll
    for (int n = 0; n < 4; ++n)
      bfr[n] = *(const s16x8*)(sB + (wc*64 + n*16 + l15)*32 + kg*8);
    #pragma unroll
    for (int m = 0; m < 4; ++m)
      #pragma unroll
      for (int n = 0; n < 4; ++n)
        acc[m][n] = __builtin_amdgcn_mfma_f32_16x16x32_bf16(
            __builtin_bit_cast(bf16x8, af[m]),
            __builtin_bit_cast(bf16x8, bfr[n]),
            acc[m][n], 0, 0, 0);
  }
  #pragma unroll
  for (int m = 0; m < 4; ++m)
    #pragma unroll
    for (int n = 0; n < 4; ++n)
      #pragma unroll
      for (int r = 0; r < 4; ++r){
        const int row = bm*128 + wr*64 + m*16 + kg*4 + r;
        const int col = bn*128 + wc*64 + n*16 + l15;
        float val = acc[m][n][r];
        if constexpr (MODE == 0){
          val = val * sigm(val);
          ((u16*)Cout)[(size_t)row*N + col] = f2bf(val);
        } else if constexpr (MODE == 1){
          val = sigm(val + bias[col]);
          ((u16*)Cout)[(size_t)row*N + col] = f2bf(val);
        } else if constexpr (MODE == 2){
          val = val + bias[col];
          ((u16*)Cout)[(size_t)row*N + col] = f2bf(val);
        } else {
          ((float*)Cout)[(size_t)row*N + col] = val;
        }
      }
}

// ---------------------------------------------------------------------------
// chunk-parallel linear scan: h_t = a_t * h_{t-1} + (1-a_t) * v_t
// ---------------------------------------------------------------------------
__global__ __launch_bounds__(256) void scan_pass1(
    const u16* __restrict__ alpha, const u16* __restrict__ v,
    float* __restrict__ P, float* __restrict__ H)
{
  const int e = blockIdx.x*256 + threadIdx.x;
  const int c = blockIdx.y;
  const size_t base = (size_t)c*CHUNK*EDIM + e;
  float p = 1.f, h = 0.f;
  #pragma unroll 8
  for (int t = 0; t < CHUNK; ++t){
    float a  = bf2f(alpha[base + (size_t)t*EDIM]);
    float vv = bf2f(v[base + (size_t)t*EDIM]);
    p *= a;
    h = a*h + (1.f - a)*vv;
  }
  P[(size_t)c*EDIM + e] = p;
  H[(size_t)c*EDIM + e] = h;
}

__global__ __launch_bounds__(256) void scan_pass2(
    const float* __restrict__ P, const float* __restrict__ H,
    const float* __restrict__ h0, float* __restrict__ hstart,
    float* __restrict__ hfinal)
{
  const int e = blockIdx.x*256 + threadIdx.x;
  float hs = h0[e];
  for (int c = 0; c < NCHUNK; ++c){
    hstart[(size_t)c*EDIM + e] = hs;
    hs = P[(size_t)c*EDIM + e]*hs + H[(size_t)c*EDIM + e];
  }
  hfinal[e] = hs;
}

__global__ __launch_bounds__(256) void scan_pass3(
    const u16* __restrict__ alpha, const u16* __restrict__ v,
    const float* __restrict__ hstart, u16* __restrict__ outs)
{
  const int e = blockIdx.x*256 + threadIdx.x;
  const int c = blockIdx.y;
  const size_t base = (size_t)c*CHUNK*EDIM + e;
  float h = hstart[(size_t)c*EDIM + e];
  #pragma unroll 8
  for (int t = 0; t < CHUNK; ++t){
    float a  = bf2f(alpha[base + (size_t)t*EDIM]);
    float vv = bf2f(v[base + (size_t)t*EDIM]);
    h = a*h + (1.f - a)*vv;
    float o = h*h*sigm(h);            // h * silu(h)
    outs[base + (size_t)t*EDIM] = f2bf(o);   // aliases v: write-after-read, same slot
  }
}

// ---------------------------------------------------------------------------
// all 4 weights f32 -> bf16 in ONE launch; dst = wib|wab|wvb|wob contiguous
// segment sizes (float4 units): 512K | 1M | 1M | 512K  (total 3M)
__global__ __launch_bounds__(256) void cvt_w4(
    const float* __restrict__ s0, const float* __restrict__ s1,
    const float* __restrict__ s2, const float* __restrict__ s3,
    u16* __restrict__ dst)
{
  const int i = blockIdx.x*256 + threadIdx.x;    // float4 index, concatenated
  const float* s; int j;
  if      (i <   (1<<19)) { s = s0; j = i; }
  else if (i < 3*(1<<19)) { s = s1; j = i -   (1<<19); }
  else if (i < 5*(1<<19)) { s = s2; j = i - 3*(1<<19); }
  else                    { s = s3; j = i - 5*(1<<19); }
  const float4 f = ((const float4*)s)[j];
  u32 w0 = (u32)f2bf(f.x) | ((u32)f2bf(f.y) << 16);
  u32 w1 = (u32)f2bf(f.z) | ((u32)f2bf(f.w) << 16);
  ((uint2*)dst)[i] = make_uint2(w0, w1);
}

// x [B][T][D] f32 -> bf16 time-major rows (t*8+b)
__global__ __launch_bounds__(256) void cvt_x_tm(
    const float* __restrict__ src, u16* __restrict__ dst)
{
  const int i = blockIdx.x*256 + threadIdx.x;    // float4 index
  const int d4  = i & 255;                        // 256 float4 per row
  const int rin = i >> 8;                         // b*TSEQ + t
  const int b = rin >> 11, tt = rin & (TSEQ-1);
  const int rout = tt*BATCH + b;
  const float4 f = ((const float4*)src)[i];
  u32 w0 = (u32)f2bf(f.x) | ((u32)f2bf(f.y) << 16);
  u32 w1 = (u32)f2bf(f.z) | ((u32)f2bf(f.w) << 16);
  ((uint2*)dst)[(size_t)rout*256 + d4] = make_uint2(w0, w1);
}

// ---------------------------------------------------------------------------
extern "C" void kernel_launch(void* const* d_in, const int* in_sizes, int n_in,
                              void* d_out, int out_size, void* d_ws, size_t ws_size,
                              hipStream_t stream)
{
  const float* x     = (const float*)d_in[0];
  const float* h0    = (const float*)d_in[1];
  const float* W_in  = (const float*)d_in[2];
  const float* W_al  = (const float*)d_in[3];
  const float* b_al  = (const float*)d_in[4];
  const float* W_v   = (const float*)d_in[5];
  const float* b_v   = (const float*)d_in[6];
  const float* W_out = (const float*)d_in[7];

  float* out  = (float*)d_out;
  float* hfin = out + (size_t)MROWS*D_MODEL;   // h_final tail of d_out

  const size_t SZ_ACT = (size_t)MROWS*D_INNER*2;   // 67,108,864 B
  const size_t SZ_ST  = (size_t)NCHUNK*EDIM*4;     //  4,194,304 B
  const size_t SZ_WI  = (size_t)D_INNER*D_MODEL*2; //  4 MB
  const size_t SZ_WA  = (size_t)D_INNER*D_INNER*2; //  8 MB
  const size_t need_min  = 3*SZ_ACT + 3*SZ_ST;                   // ~214 MB (proven)
  const size_t need_fast = need_min + 2*SZ_WI + 2*SZ_WA + 8192;  // ~239 MB (proven)

  if (ws_size < need_min) return;

  char* ws = (char*)d_ws;
  auto carve = [&](size_t bytes){
    char* p = ws; ws += (bytes + 255) & ~(size_t)255; return p;
  };
  u16* xp   = (u16*)carve(SZ_ACT);   // silu(in_proj), layout [T, B*D_inner]
  u16* alp  = (u16*)carve(SZ_ACT);
  u16* vv   = (u16*)carve(SZ_ACT);   // v; pass3 overwrites in place with outs
  float* P  = (float*)carve(SZ_ST);
  float* H  = (float*)carve(SZ_ST);
  float* hs = (float*)carve(SZ_ST);

  const dim3 gScan(EDIM/256, NCHUNK);

  if (ws_size >= need_fast){
    // ---- fast path: bf16 weights (wib|wab|wvb|wob contiguous; wab||wvb =>
    // fused N=4096 GEMM), time-major bf16 x aliasing alp (lifetime ends
    // before the alpha write).  All GEMM staging = pure global_load_lds.
    u16* wib = (u16*)carve(SZ_WI);
    u16* wab = (u16*)carve(SZ_WA);
    u16* wvb = (u16*)carve(SZ_WA);   // = wab + D_INNER rows (contiguous)
    u16* wob = (u16*)carve(SZ_WI);
    u16* xb  = alp;
    (void)wvb; (void)wob;

    cvt_x_tm<<<(MROWS*D_MODEL/4)/256, 256, 0, stream>>>(x, xb);
    cvt_w4<<<6*(1<<19)/256, 256, 0, stream>>>(W_in, W_al, W_v, W_out, wib);

    gemm256<0, D_MODEL, D_INNER><<<dim3(MROWS/256, D_INNER/256), 512, 0, stream>>>(
        xb, wib, nullptr, nullptr, xp, nullptr);
    gemm256<4, D_INNER, 2*D_INNER><<<dim3(MROWS/256, 2*D_INNER/256), 512, 0, stream>>>(
        xp, wab, b_al, b_v, alp, vv);

    scan_pass1<<<gScan, 256, 0, stream>>>(alp, vv, P, H);
    scan_pass2<<<EDIM/256, 256, 0, stream>>>(P, H, h0, hs, hfin);
    scan_pass3<<<gScan, 256, 0, stream>>>(alp, vv, hs, vv);

    gemm256<3, D_INNER, D_MODEL><<<dim3(MROWS/256, D_MODEL/256), 512, 0, stream>>>(
        vv, wob, nullptr, nullptr, out, nullptr);
  } else {
    // ---- fallback: round-2 proven path (cvt in staging) ----
    const dim3 gBig(MROWS/128, D_INNER/128);
    const dim3 gOut(MROWS/128, D_MODEL/128);
    gemm_bt<0, D_MODEL, D_INNER, false, false><<<gBig, 256, 0, stream>>>(x,  W_in, nullptr, xp);
    gemm_bt<1, D_INNER, D_INNER, true,  false><<<gBig, 256, 0, stream>>>(xp, W_al, b_al,    alp);
    gemm_bt<2, D_INNER, D_INNER, true,  false><<<gBig, 256, 0, stream>>>(xp, W_v,  b_v,     vv);

    scan_pass1<<<gScan, 256, 0, stream>>>(alp, vv, P, H);
    scan_pass2<<<EDIM/256, 256, 0, stream>>>(P, H, h0, hs, hfin);
    scan_pass3<<<gScan, 256, 0, stream>>>(alp, vv, hs, vv);

    gemm_bt<3, D_INNER, D_MODEL, true, false><<<gOut, 256, 0, stream>>>(vv, W_out, nullptr, out);
  }
}